// Round 3
// baseline (560.221 us; speedup 1.0000x reference)
//
#include <hip/hip_runtime.h>
#include <hip/hip_bf16.h>
#include <cmath>

typedef unsigned short u16;
typedef __attribute__((ext_vector_type(8))) short short8;
typedef __attribute__((ext_vector_type(4))) float f32x4;

#define DM 1024
#define NH 16
#define DH 64
#define DFF 4096
#define BB 4
#define TT 2048
#define MROWS (BB*TT)

__device__ __forceinline__ float bu2f(u16 u) {
    union { float f; unsigned v; } c; c.v = ((unsigned)u) << 16; return c.f;
}
__device__ __forceinline__ u16 f2bu(float f) {
    __hip_bfloat16 h = __float2bfloat16(f);
    union { __hip_bfloat16 h; u16 u; } c; c.h = h; return c.u;
}
__device__ __forceinline__ void async_copy16(const u16* g, u16* l) {
    __builtin_amdgcn_global_load_lds((const __attribute__((address_space(1))) void*)g,
                                     (__attribute__((address_space(3))) void*)l, 16, 0, 0);
}

// ---------------- LayerNorm: fp32 in -> bf16 out ----------------
__global__ void ln_kernel(const float* __restrict__ x, const float* __restrict__ gamma,
                          const float* __restrict__ beta, u16* __restrict__ out)
{
    int row = blockIdx.x;
    int tid = threadIdx.x;
    float4 v4 = ((const float4*)(x + (size_t)row * DM))[tid];
    float v[4] = { v4.x, v4.y, v4.z, v4.w };
    float s = v[0] + v[1] + v[2] + v[3];
    float ss = v[0]*v[0] + v[1]*v[1] + v[2]*v[2] + v[3]*v[3];
    #pragma unroll
    for (int o = 32; o > 0; o >>= 1) { s += __shfl_down(s, o); ss += __shfl_down(ss, o); }
    __shared__ float red[8];
    int w = tid >> 6;
    if ((tid & 63) == 0) { red[w] = s; red[4 + w] = ss; }
    __syncthreads();
    s  = red[0] + red[1] + red[2] + red[3];
    ss = red[4] + red[5] + red[6] + red[7];
    float mu  = s * (1.0f / DM);
    float var = ss * (1.0f / DM) - mu * mu;
    float rstd = rsqrtf(var + 1e-5f);
    float4 g4 = ((const float4*)gamma)[tid];
    float4 b4 = ((const float4*)beta)[tid];
    float g[4] = { g4.x, g4.y, g4.z, g4.w };
    float b[4] = { b4.x, b4.y, b4.z, b4.w };
    ushort4 o4;
    u16* op = (u16*)&o4;
    #pragma unroll
    for (int i = 0; i < 4; i++) op[i] = f2bu((v[i] - mu) * rstd * g[i] + b[i]);
    ((ushort4*)(out + (size_t)row * DM))[tid] = o4;
}

// ---------------- Transposes + fp32->bf16 ----------------
__global__ void transpose4_f2b(const float* __restrict__ w0, const float* __restrict__ w1,
                               const float* __restrict__ w2, const float* __restrict__ w3,
                               u16* __restrict__ outQKV, u16* __restrict__ outO)
{
    __shared__ u16 tile[32][33];
    const float* in = (blockIdx.z == 0) ? w0 : (blockIdx.z == 1) ? w1
                     : (blockIdx.z == 2) ? w2 : w3;
    u16* out = (blockIdx.z < 3) ? (outQKV + (size_t)blockIdx.z * DM * DM) : outO;
    int bx = blockIdx.x * 32;
    int by = blockIdx.y * 32;
    int tx = threadIdx.x, ty = threadIdx.y;  // 32 x 8
    #pragma unroll
    for (int i = 0; i < 32; i += 8)
        tile[ty + i][tx] = f2bu(in[(size_t)(by + ty + i) * DM + bx + tx]);
    __syncthreads();
    #pragma unroll
    for (int i = 0; i < 32; i += 8)
        out[(size_t)(bx + ty + i) * DM + by + tx] = tile[tx][ty + i];
}

__global__ void transpose_f2b(const float* __restrict__ in, u16* __restrict__ out,
                              int R, int C)
{
    __shared__ u16 tile[32][33];
    int bx = blockIdx.x * 32;
    int by = blockIdx.y * 32;
    int tx = threadIdx.x, ty = threadIdx.y;  // 32 x 8
    #pragma unroll
    for (int i = 0; i < 32; i += 8)
        tile[ty + i][tx] = f2bu(in[(size_t)(by + ty + i) * C + bx + tx]);
    __syncthreads();
    #pragma unroll
    for (int i = 0; i < 32; i += 8)
        out[(size_t)(bx + ty + i) * R + by + tx] = tile[tx][ty + i];
}

// ---------------- GEMM: BK=64, XOR-swizzled LDS + XCD-aware block swizzle ----------------
#define BM 128
#define BN 128
#define BK 64

template<int EPI>
__global__ void gemm_bt(
    const u16* __restrict__ A, const u16* __restrict__ Bt,
    const float* __restrict__ bias, const float* __restrict__ bias2,
    const float* __restrict__ bias3, void* __restrict__ Cv,
    const float* __restrict__ res, const float* __restrict__ x0,
    const float* __restrict__ gate, int M, int N, int K)
{
    __shared__ __align__(16) u16 As[BM * BK];
    __shared__ __align__(16) u16 Bs[BN * BK];
    int tid = threadIdx.x;
    int lane = tid & 63, wave = tid >> 6;
    int wm = (wave & 1) * 64, wn = (wave >> 1) * 64;
    int lm = lane & 15, quad = lane >> 4;

    // XCD-aware bijective swizzle (T1): all grids here have nwg % 8 == 0.
    unsigned nbx = gridDim.x;
    unsigned nwg = nbx * gridDim.y;
    unsigned orig = blockIdx.y * nbx + blockIdx.x;
    unsigned swz = (orig & 7) * (nwg >> 3) + (orig >> 3);
    unsigned bxi = swz % nbx, byi = swz / nbx;

    size_t row0 = (size_t)bxi * BM;
    size_t col0 = (size_t)byi * BN;

    int sr = tid >> 3;                              // 0..31
    int scol = (((tid & 7) ^ (sr & 7)) * 8);        // swizzled source col
    const u16* Ag = A  + (row0 + sr) * (size_t)K + scol;
    const u16* Bg = Bt + (col0 + sr) * (size_t)K + scol;
    u16* Asl = As + tid * 8;
    u16* Bsl = Bs + tid * 8;

    int fc0 = ((0 * 4 + quad) ^ (lm & 7)) * 8;
    int fc1 = ((1 * 4 + quad) ^ (lm & 7)) * 8;

    f32x4 acc[4][4];
    #pragma unroll
    for (int i = 0; i < 4; i++)
        #pragma unroll
        for (int j = 0; j < 4; j++)
            acc[i][j] = (f32x4){0.f, 0.f, 0.f, 0.f};

    for (int k0 = 0; k0 < K; k0 += BK) {
        __syncthreads();
        async_copy16(Ag + k0,                  Asl);
        async_copy16(Ag + (size_t)32 * K + k0, Asl + 32 * BK);
        async_copy16(Ag + (size_t)64 * K + k0, Asl + 64 * BK);
        async_copy16(Ag + (size_t)96 * K + k0, Asl + 96 * BK);
        async_copy16(Bg + k0,                  Bsl);
        async_copy16(Bg + (size_t)32 * K + k0, Bsl + 32 * BK);
        async_copy16(Bg + (size_t)64 * K + k0, Bsl + 64 * BK);
        async_copy16(Bg + (size_t)96 * K + k0, Bsl + 96 * BK);
        __syncthreads();
        #pragma unroll
        for (int ks = 0; ks < 2; ks++) {
            int fc = ks ? fc1 : fc0;
            short8 af[4], bfr[4];
            #pragma unroll
            for (int t = 0; t < 4; t++) {
                af[t]  = *(const short8*)&As[(wm + t * 16 + lm) * BK + fc];
                bfr[t] = *(const short8*)&Bs[(wn + t * 16 + lm) * BK + fc];
            }
            #pragma unroll
            for (int mt = 0; mt < 4; mt++)
                #pragma unroll
                for (int nt = 0; nt < 4; nt++)
                    acc[mt][nt] = __builtin_amdgcn_mfma_f32_16x16x32_bf16(
                        af[mt], bfr[nt], acc[mt][nt], 0, 0, 0);
        }
    }

    u16*   C16 = (u16*)Cv;
    float* Cf  = (float*)Cv;

    const float* bb = bias;
    size_t csub = 0;
    if (EPI == 0 && bias2 != nullptr) {
        size_t cbase = col0 + wn;
        if (cbase >= 2048)      { bb = bias3; csub = 2048; }
        else if (cbase >= 1024) { bb = bias2; csub = 1024; }
    }

    #pragma unroll
    for (int mt = 0; mt < 4; mt++) {
        #pragma unroll
        for (int nt = 0; nt < 4; nt++) {
            #pragma unroll
            for (int r = 0; r < 4; r++) {
                size_t row = row0 + wm + mt * 16 + quad * 4 + r;
                size_t col = col0 + wn + nt * 16 + lm;
                size_t idx = row * (size_t)N + col;
                float v = acc[mt][nt][r] + bb[col - csub];
                if (EPI == 0) {
                    C16[idx] = f2bu(v);
                } else if (EPI == 1) {
                    Cf[idx] = v + res[idx];
                } else if (EPI == 2) {
                    v = 0.5f * v * (1.0f + erff(v * 0.70710678118f));
                    C16[idx] = f2bu(v);
                } else {
                    float xv  = x0[idx];
                    float x1v = res[idx];
                    float g   = gate[row >> 11];
                    Cf[idx] = xv + g * (x1v + v - xv);
                }
            }
        }
    }
}

// ---------------- MFMA flash attention: merged pairs + XOR-swizzled LDS ----------------
// ROUND-3: AVS=72 padding gave 8-way conflicts on K staging (stride 36 words ->
// bank 4*lane%32) and 4-way on V-transpose writes: 1.19e7 conflict cycles = 16%
// of attn time. New layout: [64][64] u16 (128B rows), XOR swizzle at 16B granule:
// col8 ^= (row&7), applied on BOTH write and read (same involution, rule #21).
// Staging writes now cover all 32 banks per 8-lane phase; frag reads <=2-way (free).
// Softmax mask split into wave-uniform clean/masked paths (mz_ uniform per wave).
#define SW8(row, c8) ((((c8) ^ ((row) & 7)) * 8))

#define TILE_STEP(O, L, A0, A1, QW, QV, KB) do {                                   \
    f32x4 s_[4];                                                                   \
    _Pragma("unroll")                                                              \
    for (int ks = 0; ks < 4; ks++) s_[ks] = (f32x4){0.f, 0.f, 0.f, 0.f};           \
    _Pragma("unroll")                                                              \
    for (int ks = 0; ks < 4; ks++) {                                               \
        int kr_ = ks * 16 + lm;                                                    \
        short8 k0_ = *(const short8*)&Kl[kr_][SW8(lm, quad)];                      \
        short8 k1_ = *(const short8*)&Kl[kr_][SW8(lm, 4 + quad)];                  \
        s_[ks] = __builtin_amdgcn_mfma_f32_16x16x32_bf16(k0_, (A0), s_[ks], 0, 0, 0); \
        s_[ks] = __builtin_amdgcn_mfma_f32_16x16x32_bf16(k1_, (A1), s_[ks], 0, 0, 0); \
    }                                                                              \
    bool mz_ = ((KB) + 63 > (QW));                                                 \
    if (!mz_) {                                                                    \
        _Pragma("unroll")                                                          \
        for (int ks = 0; ks < 4; ks++) {                                           \
            ushort4 pk_;                                                           \
            u16* pp_ = (u16*)&pk_;                                                 \
            _Pragma("unroll")                                                      \
            for (int r = 0; r < 4; r++)                                            \
                pp_[r] = f2bu(exp2f(fmaf(s_[ks][r], sc, -FM)));                    \
            *(ushort4*)&Pl[w][lm][SW8(lm, ks * 2 + (quad >> 1)) + (quad & 1) * 4] = pk_; \
        }                                                                          \
    } else {                                                                       \
        _Pragma("unroll")                                                          \
        for (int ks = 0; ks < 4; ks++) {                                           \
            int kbase_ = (KB) + ks * 16 + quad * 4;                                \
            ushort4 pk_;                                                           \
            u16* pp_ = (u16*)&pk_;                                                 \
            _Pragma("unroll")                                                      \
            for (int r = 0; r < 4; r++) {                                          \
                float v_ = fmaf(s_[ks][r], sc, -FM);                               \
                if (kbase_ + r > (QV)) v_ = -INFINITY;                             \
                pp_[r] = f2bu(exp2f(v_));                                          \
            }                                                                      \
            *(ushort4*)&Pl[w][lm][SW8(lm, ks * 2 + (quad >> 1)) + (quad & 1) * 4] = pk_; \
        }                                                                          \
    }                                                                              \
    _Pragma("unroll")                                                              \
    for (int kc = 0; kc < 2; kc++) {                                               \
        short8 ap_ = *(const short8*)&Pl[w][lm][SW8(lm, kc * 4 + quad)];           \
        _Pragma("unroll")                                                          \
        for (int ds = 0; ds < 4; ds++) {                                           \
            short8 bv_ = *(const short8*)&Vt[ds * 16 + lm][SW8(lm, kc * 4 + quad)]; \
            O[ds] = __builtin_amdgcn_mfma_f32_16x16x32_bf16(ap_, bv_, O[ds], 0, 0, 0); \
        }                                                                          \
        L = __builtin_amdgcn_mfma_f32_16x16x32_bf16(ap_, ones, L, 0, 0, 0);        \
    }                                                                              \
} while (0)

__global__ __launch_bounds__(256, 4) void attn_mfma(
    const u16* __restrict__ QKV, u16* __restrict__ ctx)
{
    __shared__ __align__(16) u16 Kl[64][64];      // [key][dim], XOR-swizzled
    __shared__ __align__(16) u16 Vt[64][64];      // [dim][key], XOR-swizzled
    __shared__ __align__(16) u16 Pl[4][16][64];   // per-wave P[q][k], XOR-swizzled

    const int LD = 3 * DM;
    int tid = threadIdx.x, lane = tid & 63, w = tid >> 6;
    int lm = lane & 15, quad = lane >> 4;

    // XCD swizzle: 16 consecutive pair-blocks share one (b,h)'s K/V (512KB);
    // co-locate them on one XCD's L2 instead of round-robin over 8.
    unsigned orig = blockIdx.x;                    // 1024 blocks, 1024%8==0
    int bi = (int)((orig & 7) * 128 + (orig >> 3));
    int pair = bi & 15, h = (bi >> 4) & 15, b = bi >> 8;
    int t1 = 31 - pair, t2 = pair;                 // t2 < t1

    const size_t hoff = (size_t)h * DH;
    const u16* Qp = QKV + (size_t)b * TT * LD + hoff;
    const u16* Kp = Qp + DM;
    const u16* Vp = Qp + 2 * DM;

    int qw1 = t1 * 64 + w * 16, qv1 = qw1 + lm;
    int qw2 = t2 * 64 + w * 16, qv2 = qw2 + lm;

    short8 aq1_0 = *(const short8*)(Qp + (size_t)(qw1 + lm) * LD + quad * 8);
    short8 aq1_1 = *(const short8*)(Qp + (size_t)(qw1 + lm) * LD + 32 + quad * 8);
    short8 aq2_0 = *(const short8*)(Qp + (size_t)(qw2 + lm) * LD + quad * 8);
    short8 aq2_1 = *(const short8*)(Qp + (size_t)(qw2 + lm) * LD + 32 + quad * 8);

    int kkey = tid & 63, kdim = (tid >> 6) * 16;       // K: 1 key x 16 dims
    int vkey = (tid & 31) * 2, vdim = (tid >> 5) * 8;  // V: 2 keys x 8 dims

    const u16* kb0 = Kp + (size_t)kkey * LD + kdim;
    const u16* vb0 = Vp + (size_t)vkey * LD + vdim;
    const u16* vb1 = Vp + (size_t)(vkey + 1) * LD + vdim;

    const float sc = 0.18033688011f;   // log2(e)/8
    const float FM = 24.0f;            // fixed max (exp2 domain)
    const short s1 = (short)0x3F80;    // bf16 1.0
    const short8 ones = (short8){s1, s1, s1, s1, s1, s1, s1, s1};

    f32x4 o1[4], o2[4], l1, l2;
    #pragma unroll
    for (int ds = 0; ds < 4; ds++) {
        o1[ds] = (f32x4){0.f, 0.f, 0.f, 0.f};
        o2[ds] = (f32x4){0.f, 0.f, 0.f, 0.f};
    }
    l1 = (f32x4){0.f, 0.f, 0.f, 0.f};
    l2 = (f32x4){0.f, 0.f, 0.f, 0.f};

    uint4 kr0 = *(const uint4*)(kb0);
    uint4 kr1 = *(const uint4*)(kb0 + 8);
    uint4 vr0 = *(const uint4*)(vb0);
    uint4 vr1 = *(const uint4*)(vb1);

    // K staging slots: two 16B pieces at c8 = w*2, w*2+1, swizzled by key row.
    int ksw0 = SW8(kkey, (tid >> 6) * 2);
    int ksw1 = SW8(kkey, (tid >> 6) * 2 + 1);
    // V staging: ushort2 at col vkey within row (vdim+j); c8 = vkey>>3,
    // in-slot offset vkey&7; row&7 == j (vdim is a multiple of 8).
    int vc8 = vkey >> 3, vlo = vkey & 7;

    int nch = t1 + 1;
    for (int c = 0; c < nch; c++) {
        int kb = c * 64;
        __syncthreads();
        *(uint4*)&Kl[kkey][ksw0] = kr0;
        *(uint4*)&Kl[kkey][ksw1] = kr1;
        {
            const u16* p0 = (const u16*)&vr0;
            const u16* p1 = (const u16*)&vr1;
            #pragma unroll
            for (int j = 0; j < 8; j++) {
                ushort2 pk = { p0[j], p1[j] };
                *(ushort2*)&Vt[vdim + j][((vc8 ^ j) * 8) + vlo] = pk;
            }
        }
        __syncthreads();

        {
            size_t offn = (c + 1 < nch) ? (size_t)(c + 1) * 64 * LD : 0;
            kr0 = *(const uint4*)(kb0 + offn);
            kr1 = *(const uint4*)(kb0 + offn + 8);
            vr0 = *(const uint4*)(vb0 + offn);
            vr1 = *(const uint4*)(vb1 + offn);
        }

        TILE_STEP(o1, l1, aq1_0, aq1_1, qw1, qv1, kb);
        if (c <= t2)
            TILE_STEP(o2, l2, aq2_0, aq2_1, qw2, qv2, kb);
    }

    // epilogue: both tiles
    {
        float inv[4];
        #pragma unroll
        for (int r = 0; r < 4; r++) inv[r] = 1.0f / l1[r];
        #pragma unroll
        for (int ds = 0; ds < 4; ds++)
            #pragma unroll
            for (int r = 0; r < 4; r++) {
                size_t row = (size_t)(b * TT + qw1 + quad * 4 + r);
                ctx[row * DM + hoff + ds * 16 + lm] = f2bu(o1[ds][r] * inv[r]);
            }
        #pragma unroll
        for (int r = 0; r < 4; r++) inv[r] = 1.0f / l2[r];
        #pragma unroll
        for (int ds = 0; ds < 4; ds++)
            #pragma unroll
            for (int r = 0; r < 4; r++) {
                size_t row = (size_t)(b * TT + qw2 + quad * 4 + r);
                ctx[row * DM + hoff + ds * 16 + lm] = f2bu(o2[ds][r] * inv[r]);
            }
    }
}

extern "C" void kernel_launch(void* const* d_in, const int* in_sizes, int n_in,
                              void* d_out, int out_size, void* d_ws, size_t ws_size,
                              hipStream_t stream)
{
    const float* x    = (const float*)d_in[0];
    const float* gate = (const float*)d_in[1];
    const float* Wq   = (const float*)d_in[2];
    const float* bq   = (const float*)d_in[3];
    const float* Wk   = (const float*)d_in[4];
    const float* bk   = (const float*)d_in[5];
    const float* Wv   = (const float*)d_in[6];
    const float* bv   = (const float*)d_in[7];
    const float* Wo   = (const float*)d_in[8];
    const float* bo   = (const float*)d_in[9];
    const float* W1   = (const float*)d_in[10];
    const float* b1   = (const float*)d_in[11];
    const float* W2   = (const float*)d_in[12];
    const float* b2   = (const float*)d_in[13];
    const float* gamma1 = (const float*)d_in[14];
    const float* beta1  = (const float*)d_in[15];
    const float* gamma2 = (const float*)d_in[16];
    const float* beta2  = (const float*)d_in[17];
    float* out = (float*)d_out;

    char* ws = (char*)d_ws;
    const size_t MB = 1024 * 1024;
    u16* WtQKV = (u16*)(ws + 0 * MB);
    u16* WtO   = (u16*)(ws + 6 * MB);
    u16* Wt1   = (u16*)(ws + 8 * MB);
    u16* Wt2   = (u16*)(ws + 16 * MB);
    u16* h     = (u16*)(ws + 24 * MB);
    u16* ctx   = (u16*)(ws + 24 * MB);
    u16* QKVb  = (u16*)(ws + 40 * MB);
    float* x1  = (float*)(ws + 40 * MB);
    u16* h2    = (u16*)(ws + 72 * MB);
    u16* ff    = (u16*)(ws + 88 * MB);

    dim3 tb(32, 8);
    transpose4_f2b<<<dim3(32, 32, 4), tb, 0, stream>>>(Wq, Wk, Wv, Wo, WtQKV, WtO);
    transpose_f2b<<<dim3(DFF / 32, DM / 32), tb, 0, stream>>>(W1, Wt1, DM, DFF);
    transpose_f2b<<<dim3(DM / 32, DFF / 32), tb, 0, stream>>>(W2, Wt2, DFF, DM);

    ln_kernel<<<MROWS, 256, 0, stream>>>(x, gamma1, beta1, h);

    gemm_bt<0><<<dim3(MROWS / BM, 3 * DM / BN), 256, 0, stream>>>(
        h, WtQKV, bq, bk, bv, QKVb, nullptr, nullptr, nullptr, MROWS, 3 * DM, DM);

    attn_mfma<<<BB * NH * 16, 256, 0, stream>>>(QKVb, ctx);

    gemm_bt<1><<<dim3(MROWS / BM, DM / BN), 256, 0, stream>>>(
        ctx, WtO, bo, nullptr, nullptr, x1, x, nullptr, nullptr, MROWS, DM, DM);

    ln_kernel<<<MROWS, 256, 0, stream>>>(x1, gamma2, beta2, h2);

    gemm_bt<2><<<dim3(MROWS / BM, DFF / BN), 256, 0, stream>>>(
        h2, Wt1, b1, nullptr, nullptr, ff, nullptr, nullptr, nullptr, MROWS, DFF, DM);

    gemm_bt<3><<<dim3(MROWS / BM, DM / BN), 256, 0, stream>>>(
        ff, Wt2, b2, nullptr, nullptr, out, x1, x, gate, MROWS, DM, DFF);
}

// Round 4
// 557.342 us; speedup vs baseline: 1.0052x; 1.0052x over previous
//
#include <hip/hip_runtime.h>
#include <hip/hip_bf16.h>
#include <cmath>

typedef unsigned short u16;
typedef __attribute__((ext_vector_type(8))) short short8;
typedef __attribute__((ext_vector_type(4))) float f32x4;
typedef __attribute__((ext_vector_type(16))) float f32x16;

#define DM 1024
#define NH 16
#define DH 64
#define DFF 4096
#define BB 4
#define TT 2048
#define MROWS (BB*TT)

__device__ __forceinline__ float bu2f(u16 u) {
    union { float f; unsigned v; } c; c.v = ((unsigned)u) << 16; return c.f;
}
__device__ __forceinline__ u16 f2bu(float f) {
    __hip_bfloat16 h = __float2bfloat16(f);
    union { __hip_bfloat16 h; u16 u; } c; c.h = h; return c.u;
}
__device__ __forceinline__ void async_copy16(const u16* g, u16* l) {
    __builtin_amdgcn_global_load_lds((const __attribute__((address_space(1))) void*)g,
                                     (__attribute__((address_space(3))) void*)l, 16, 0, 0);
}

// ---------------- LayerNorm: fp32 in -> bf16 out ----------------
__global__ void ln_kernel(const float* __restrict__ x, const float* __restrict__ gamma,
                          const float* __restrict__ beta, u16* __restrict__ out)
{
    int row = blockIdx.x;
    int tid = threadIdx.x;
    float4 v4 = ((const float4*)(x + (size_t)row * DM))[tid];
    float v[4] = { v4.x, v4.y, v4.z, v4.w };
    float s = v[0] + v[1] + v[2] + v[3];
    float ss = v[0]*v[0] + v[1]*v[1] + v[2]*v[2] + v[3]*v[3];
    #pragma unroll
    for (int o = 32; o > 0; o >>= 1) { s += __shfl_down(s, o); ss += __shfl_down(ss, o); }
    __shared__ float red[8];
    int w = tid >> 6;
    if ((tid & 63) == 0) { red[w] = s; red[4 + w] = ss; }
    __syncthreads();
    s  = red[0] + red[1] + red[2] + red[3];
    ss = red[4] + red[5] + red[6] + red[7];
    float mu  = s * (1.0f / DM);
    float var = ss * (1.0f / DM) - mu * mu;
    float rstd = rsqrtf(var + 1e-5f);
    float4 g4 = ((const float4*)gamma)[tid];
    float4 b4 = ((const float4*)beta)[tid];
    float g[4] = { g4.x, g4.y, g4.z, g4.w };
    float b[4] = { b4.x, b4.y, b4.z, b4.w };
    ushort4 o4;
    u16* op = (u16*)&o4;
    #pragma unroll
    for (int i = 0; i < 4; i++) op[i] = f2bu((v[i] - mu) * rstd * g[i] + b[i]);
    ((ushort4*)(out + (size_t)row * DM))[tid] = o4;
}

// ---------------- Transposes + fp32->bf16 ----------------
__global__ void transpose4_f2b(const float* __restrict__ w0, const float* __restrict__ w1,
                               const float* __restrict__ w2, const float* __restrict__ w3,
                               u16* __restrict__ outQKV, u16* __restrict__ outO)
{
    __shared__ u16 tile[32][33];
    const float* in = (blockIdx.z == 0) ? w0 : (blockIdx.z == 1) ? w1
                     : (blockIdx.z == 2) ? w2 : w3;
    u16* out = (blockIdx.z < 3) ? (outQKV + (size_t)blockIdx.z * DM * DM) : outO;
    int bx = blockIdx.x * 32;
    int by = blockIdx.y * 32;
    int tx = threadIdx.x, ty = threadIdx.y;  // 32 x 8
    #pragma unroll
    for (int i = 0; i < 32; i += 8)
        tile[ty + i][tx] = f2bu(in[(size_t)(by + ty + i) * DM + bx + tx]);
    __syncthreads();
    #pragma unroll
    for (int i = 0; i < 32; i += 8)
        out[(size_t)(bx + ty + i) * DM + by + tx] = tile[tx][ty + i];
}

__global__ void transpose_f2b(const float* __restrict__ in, u16* __restrict__ out,
                              int R, int C)
{
    __shared__ u16 tile[32][33];
    int bx = blockIdx.x * 32;
    int by = blockIdx.y * 32;
    int tx = threadIdx.x, ty = threadIdx.y;  // 32 x 8
    #pragma unroll
    for (int i = 0; i < 32; i += 8)
        tile[ty + i][tx] = f2bu(in[(size_t)(by + ty + i) * C + bx + tx]);
    __syncthreads();
    #pragma unroll
    for (int i = 0; i < 32; i += 8)
        out[(size_t)(bx + ty + i) * R + by + tx] = tile[tx][ty + i];
}

// ---------------- GEMM: BK=64, XOR-swizzled LDS (round-2 form, no block swizzle) --------
#define BM 128
#define BN 128
#define BK 64

template<int EPI>
__global__ void gemm_bt(
    const u16* __restrict__ A, const u16* __restrict__ Bt,
    const float* __restrict__ bias, const float* __restrict__ bias2,
    const float* __restrict__ bias3, void* __restrict__ Cv,
    const float* __restrict__ res, const float* __restrict__ x0,
    const float* __restrict__ gate, int M, int N, int K)
{
    __shared__ __align__(16) u16 As[BM * BK];
    __shared__ __align__(16) u16 Bs[BN * BK];
    int tid = threadIdx.x;
    int lane = tid & 63, wave = tid >> 6;
    int wm = (wave & 1) * 64, wn = (wave >> 1) * 64;
    int lm = lane & 15, quad = lane >> 4;
    size_t row0 = (size_t)blockIdx.x * BM;
    size_t col0 = (size_t)blockIdx.y * BN;

    int sr = tid >> 3;                              // 0..31
    int scol = (((tid & 7) ^ (sr & 7)) * 8);        // swizzled source col
    const u16* Ag = A  + (row0 + sr) * (size_t)K + scol;
    const u16* Bg = Bt + (col0 + sr) * (size_t)K + scol;
    u16* Asl = As + tid * 8;
    u16* Bsl = Bs + tid * 8;

    int fc0 = ((0 * 4 + quad) ^ (lm & 7)) * 8;
    int fc1 = ((1 * 4 + quad) ^ (lm & 7)) * 8;

    f32x4 acc[4][4];
    #pragma unroll
    for (int i = 0; i < 4; i++)
        #pragma unroll
        for (int j = 0; j < 4; j++)
            acc[i][j] = (f32x4){0.f, 0.f, 0.f, 0.f};

    for (int k0 = 0; k0 < K; k0 += BK) {
        __syncthreads();
        async_copy16(Ag + k0,                  Asl);
        async_copy16(Ag + (size_t)32 * K + k0, Asl + 32 * BK);
        async_copy16(Ag + (size_t)64 * K + k0, Asl + 64 * BK);
        async_copy16(Ag + (size_t)96 * K + k0, Asl + 96 * BK);
        async_copy16(Bg + k0,                  Bsl);
        async_copy16(Bg + (size_t)32 * K + k0, Bsl + 32 * BK);
        async_copy16(Bg + (size_t)64 * K + k0, Bsl + 64 * BK);
        async_copy16(Bg + (size_t)96 * K + k0, Bsl + 96 * BK);
        __syncthreads();
        #pragma unroll
        for (int ks = 0; ks < 2; ks++) {
            int fc = ks ? fc1 : fc0;
            short8 af[4], bfr[4];
            #pragma unroll
            for (int t = 0; t < 4; t++) {
                af[t]  = *(const short8*)&As[(wm + t * 16 + lm) * BK + fc];
                bfr[t] = *(const short8*)&Bs[(wn + t * 16 + lm) * BK + fc];
            }
            #pragma unroll
            for (int mt = 0; mt < 4; mt++)
                #pragma unroll
                for (int nt = 0; nt < 4; nt++)
                    acc[mt][nt] = __builtin_amdgcn_mfma_f32_16x16x32_bf16(
                        af[mt], bfr[nt], acc[mt][nt], 0, 0, 0);
        }
    }

    u16*   C16 = (u16*)Cv;
    float* Cf  = (float*)Cv;

    const float* bb = bias;
    size_t csub = 0;
    if (EPI == 0 && bias2 != nullptr) {
        size_t cbase = col0 + wn;
        if (cbase >= 2048)      { bb = bias3; csub = 2048; }
        else if (cbase >= 1024) { bb = bias2; csub = 1024; }
    }

    #pragma unroll
    for (int mt = 0; mt < 4; mt++) {
        #pragma unroll
        for (int nt = 0; nt < 4; nt++) {
            #pragma unroll
            for (int r = 0; r < 4; r++) {
                size_t row = row0 + wm + mt * 16 + quad * 4 + r;
                size_t col = col0 + wn + nt * 16 + lm;
                size_t idx = row * (size_t)N + col;
                float v = acc[mt][nt][r] + bb[col - csub];
                if (EPI == 0) {
                    C16[idx] = f2bu(v);
                } else if (EPI == 1) {
                    Cf[idx] = v + res[idx];
                } else if (EPI == 2) {
                    v = 0.5f * v * (1.0f + erff(v * 0.70710678118f));
                    C16[idx] = f2bu(v);
                } else {
                    float xv  = x0[idx];
                    float x1v = res[idx];
                    float g   = gate[row >> 11];
                    Cf[idx] = xv + g * (x1v + v - xv);
                }
            }
        }
    }
}

// ---------------- MFMA flash attention, 32x32 shapes, P never touches LDS ----------------
// Per block: one 64-query tile of one (b,h). 4 waves = (qgrp = w&1) x (keygrp = w>>1);
// each wave computes a 32q x 32key quadrant per 64-key chunk.
//   QK:  S^T = K·Q^T via mfma_32x32x16 (A = K-frag from LDS, B = Q rows in registers).
//        C-layout (m74): col=lane&31 = q, row = (reg&3)+8*(reg>>2)+4*(lane>>5) = key-local.
//   softmax: p = exp2(s*sc - FM) in registers; causal mask only on the diagonal chunk
//        where (kg==qgrp): mask is klocal > l31. Rowsum in VALU (f32, closer to ref).
//   P repack (the point of this rewrite): PV's B-operand needs 8-consecutive-key
//        granules; lane holds keys {r+8g+4hi}. Missing half lives at lane^32 exactly:
//        2x v_cvt_pk_bf16_f32 per 4-reg block + __shfl_xor(32) + cndmask assembles the
//        frag with ZERO LDS traffic (was 4 ds_write + 2 ds_read + lgkm latency per step).
//   PV:  o^T = V^T·P^T, A = V^T-frag from swizzled Vt, accumulate f32x16 per dim-group.
// Epilogue: keygrp halves merge via LDS overlay (Ol on K/V buffer), kg1 normalizes+writes.
// LDS per block 16.5KB; frag traffic per wave-chunk: 4 b128 K + 4 b128 V + staging 10.

__global__ __launch_bounds__(256, 4) void attn_mfma(
    const u16* __restrict__ QKV, u16* __restrict__ ctx)
{
    __shared__ __align__(16) u16 KV[2][64][64];   // [0]=K [key][dim], [1]=V^T [dim][key]
    __shared__ float Ls[2][32];                   // per-qgrp kg0 rowsum

    const int LD = 3 * DM;
    int tid = threadIdx.x, lane = tid & 63, w = tid >> 6;
    int qgrp = w & 1, kg = w >> 1;
    int l31 = lane & 31, hi = lane >> 5;

    // XCD-chunked, heavy-first decode: 2048 blocks = 4b x 16h x 32t.
    unsigned orig = blockIdx.x;
    int bi = (int)((orig & 7) * 256 + (orig >> 3));
    int b = bi >> 9, h = (bi >> 5) & 15, t = 31 - (bi & 31);

    const size_t hoff = (size_t)h * DH;
    const u16* Qp = QKV + (size_t)b * TT * LD + hoff;
    const u16* Kp = Qp + DM;
    const u16* Vp = Qp + 2 * DM;

    int q0 = t * 64 + qgrp * 32;

    // Q rows in registers: B-frag element j = Q[q0+l31][dc*16 + hi*8 + j]
    short8 aq0 = *(const short8*)(Qp + (size_t)(q0 + l31) * LD +  0 + hi * 8);
    short8 aq1 = *(const short8*)(Qp + (size_t)(q0 + l31) * LD + 16 + hi * 8);
    short8 aq2 = *(const short8*)(Qp + (size_t)(q0 + l31) * LD + 32 + hi * 8);
    short8 aq3 = *(const short8*)(Qp + (size_t)(q0 + l31) * LD + 48 + hi * 8);

    int kkey = tid & 63, kw = tid >> 6;                // K staging: 1 key x 16 dims
    int vkey = (tid & 31) * 2, vdim = (tid >> 5) * 8;  // V staging: 2 keys x 8 dims

    const u16* kb0 = Kp + (size_t)kkey * LD + kw * 16;
    const u16* vb0 = Vp + (size_t)vkey * LD + vdim;
    const u16* vb1 = Vp + (size_t)(vkey + 1) * LD + vdim;

    u16 (*Kl)[64] = KV[0];
    u16 (*Vt)[64] = KV[1];

    int ksw0 = ((kw * 2)     ^ (kkey & 7)) * 8;        // swizzled 16B granules
    int ksw1 = ((kw * 2 + 1) ^ (kkey & 7)) * 8;
    int vc8 = vkey >> 3, vlo = vkey & 7;

    const float sc = 0.18033688011f;   // log2(e)/8
    const float FM = 24.0f;            // fixed max (exp2 domain)

    f32x16 o0, o1;                      // o^T accumulators, dim groups 0/1
    #pragma unroll
    for (int j = 0; j < 16; j++) { o0[j] = 0.f; o1[j] = 0.f; }
    float lac = 0.f;

    uint4 kr0 = *(const uint4*)(kb0);
    uint4 kr1 = *(const uint4*)(kb0 + 8);
    uint4 vr0 = *(const uint4*)(vb0);
    uint4 vr1 = *(const uint4*)(vb1);

    int krow = kg * 32 + l31;          // K-frag row (key within chunk)
    int kx = krow & 7;                 // K-frag swizzle term
    int r7 = l31 & 7;                  // V-frag swizzle term (dim row & 7)

    for (int c = 0; c <= t; c++) {
        __syncthreads();
        *(uint4*)&Kl[kkey][ksw0] = kr0;
        *(uint4*)&Kl[kkey][ksw1] = kr1;
        {
            const u16* p0 = (const u16*)&vr0;
            const u16* p1 = (const u16*)&vr1;
            #pragma unroll
            for (int j = 0; j < 8; j++) {
                ushort2 pk = { p0[j], p1[j] };
                *(ushort2*)&Vt[vdim + j][((vc8 ^ j) * 8) + vlo] = pk;
            }
        }
        __syncthreads();

        {
            size_t offn = (c < t) ? (size_t)(c + 1) * 64 * LD : 0;
            kr0 = *(const uint4*)(kb0 + offn);
            kr1 = *(const uint4*)(kb0 + offn + 8);
            vr0 = *(const uint4*)(vb0 + offn);
            vr1 = *(const uint4*)(vb1 + offn);
        }

        int kb = c * 64;
        bool active = (kb + kg * 32) <= (q0 + 31);   // wave-uniform
        if (active) {
            // ---- S^T = K·Q^T over 4 dim-chunks ----
            f32x16 s;
            #pragma unroll
            for (int j = 0; j < 16; j++) s[j] = 0.f;
            {
                short8 kf0 = *(const short8*)&Kl[krow][((0 + hi) ^ kx) * 8];
                s = __builtin_amdgcn_mfma_f32_32x32x16_bf16(kf0, aq0, s, 0, 0, 0);
                short8 kf1 = *(const short8*)&Kl[krow][((2 + hi) ^ kx) * 8];
                s = __builtin_amdgcn_mfma_f32_32x32x16_bf16(kf1, aq1, s, 0, 0, 0);
                short8 kf2 = *(const short8*)&Kl[krow][((4 + hi) ^ kx) * 8];
                s = __builtin_amdgcn_mfma_f32_32x32x16_bf16(kf2, aq2, s, 0, 0, 0);
                short8 kf3 = *(const short8*)&Kl[krow][((6 + hi) ^ kx) * 8];
                s = __builtin_amdgcn_mfma_f32_32x32x16_bf16(kf3, aq3, s, 0, 0, 0);
            }

            // ---- softmax (fixed max), causal mask only when kg==qgrp on diagonal ----
            float p[16];
            bool need_mask = (c == t) && (kg == qgrp);
            if (!need_mask) {
                #pragma unroll
                for (int rg = 0; rg < 16; rg++)
                    p[rg] = exp2f(fmaf(s[rg], sc, -FM));
            } else {
                #pragma unroll
                for (int rg = 0; rg < 16; rg++) {
                    int klocal = (rg & 3) + 8 * (rg >> 2) + 4 * hi;
                    float v = fmaf(s[rg], sc, -FM);
                    if (klocal > l31) v = -INFINITY;
                    p[rg] = exp2f(v);
                }
            }
            lac += ((p[0] + p[1]) + (p[2] + p[3])) + ((p[4] + p[5]) + (p[6] + p[7]))
                 + ((p[8] + p[9]) + (p[10] + p[11])) + ((p[12] + p[13]) + (p[14] + p[15]));

            // ---- pack to bf16 pairs: pk0[g] = (p[4g],p[4g+1]), pk1[g] = (p[4g+2],p[4g+3]) ----
            unsigned pk0[4], pk1[4];
            #pragma unroll
            for (int g = 0; g < 4; g++) {
                asm("v_cvt_pk_bf16_f32 %0, %1, %2" : "=v"(pk0[g]) : "v"(p[4*g]),   "v"(p[4*g+1]));
                asm("v_cvt_pk_bf16_f32 %0, %1, %2" : "=v"(pk1[g]) : "v"(p[4*g+2]), "v"(p[4*g+3]));
            }

            // ---- PV: o^T += V^T·P^T, two K=16 chunks; P^T-frag via shfl_xor(32) ----
            #pragma unroll
            for (int kc = 0; kc < 2; kc++) {
                unsigned own0 = hi ? pk0[2*kc+1] : pk0[2*kc];
                unsigned own1 = hi ? pk1[2*kc+1] : pk1[2*kc];
                unsigned snd0 = hi ? pk0[2*kc]   : pk0[2*kc+1];
                unsigned snd1 = hi ? pk1[2*kc]   : pk1[2*kc+1];
                unsigned rc0 = (unsigned)__shfl_xor((int)snd0, 32);
                unsigned rc1 = (unsigned)__shfl_xor((int)snd1, 32);
                union { uint4 u; short8 s8; } bw;
                bw.u.x = hi ? rc0 : own0;
                bw.u.y = hi ? rc1 : own1;
                bw.u.z = hi ? own0 : rc0;
                bw.u.w = hi ? own1 : rc1;
                int vcol = ((kg * 4 + kc * 2 + hi) ^ r7) * 8;
                short8 v0 = *(const short8*)&Vt[l31][vcol];
                short8 v1 = *(const short8*)&Vt[32 + l31][vcol];
                o0 = __builtin_amdgcn_mfma_f32_32x32x16_bf16(v0, bw.s8, o0, 0, 0, 0);
                o1 = __builtin_amdgcn_mfma_f32_32x32x16_bf16(v1, bw.s8, o1, 0, 0, 0);
            }
        }
    }

    // ---- epilogue: merge keygrp halves, normalize, write ----
    lac += __shfl_xor(lac, 32);
    __syncthreads();                                    // done with Kl/Vt
    float* Ol = (float*)&KV[0][0][0];                   // [qgrp][dim 64][q 32] f32 = 16KB
    if (kg == 0) {
        #pragma unroll
        for (int rg = 0; rg < 16; rg++) {
            int dim = (rg & 3) + 8 * (rg >> 2) + 4 * hi;
            Ol[qgrp * 2048 + dim * 32 + l31]        = o0[rg];
            Ol[qgrp * 2048 + (32 + dim) * 32 + l31] = o1[rg];
        }
        if (hi == 0) Ls[qgrp][l31] = lac;
    }
    __syncthreads();
    if (kg == 1) {
        float ltot = lac + Ls[qgrp][l31];
        float inv = 1.0f / ltot;
        size_t rowbase = ((size_t)(b * TT + q0 + l31)) * DM + hoff;
        #pragma unroll
        for (int dg = 0; dg < 2; dg++) {
            #pragma unroll
            for (int g = 0; g < 4; g++) {
                ushort4 o4;
                u16* op = (u16*)&o4;
                #pragma unroll
                for (int r = 0; r < 4; r++) {
                    int rg = 4 * g + r;
                    int dim = dg * 32 + 8 * g + 4 * hi + r;
                    float part = dg ? o1[rg] : o0[rg];
                    float val = (part + Ol[qgrp * 2048 + dim * 32 + l31]) * inv;
                    op[r] = f2bu(val);
                }
                *(ushort4*)(ctx + rowbase + dg * 32 + 8 * g + 4 * hi) = o4;
            }
        }
    }
}

extern "C" void kernel_launch(void* const* d_in, const int* in_sizes, int n_in,
                              void* d_out, int out_size, void* d_ws, size_t ws_size,
                              hipStream_t stream)
{
    const float* x    = (const float*)d_in[0];
    const float* gate = (const float*)d_in[1];
    const float* Wq   = (const float*)d_in[2];
    const float* bq   = (const float*)d_in[3];
    const float* Wk   = (const float*)d_in[4];
    const float* bk   = (const float*)d_in[5];
    const float* Wv   = (const float*)d_in[6];
    const float* bv   = (const float*)d_in[7];
    const float* Wo   = (const float*)d_in[8];
    const float* bo   = (const float*)d_in[9];
    const float* W1   = (const float*)d_in[10];
    const float* b1   = (const float*)d_in[11];
    const float* W2   = (const float*)d_in[12];
    const float* b2   = (const float*)d_in[13];
    const float* gamma1 = (const float*)d_in[14];
    const float* beta1  = (const float*)d_in[15];
    const float* gamma2 = (const float*)d_in[16];
    const float* beta2  = (const float*)d_in[17];
    float* out = (float*)d_out;

    char* ws = (char*)d_ws;
    const size_t MB = 1024 * 1024;
    u16* WtQKV = (u16*)(ws + 0 * MB);
    u16* WtO   = (u16*)(ws + 6 * MB);
    u16* Wt1   = (u16*)(ws + 8 * MB);
    u16* Wt2   = (u16*)(ws + 16 * MB);
    u16* h     = (u16*)(ws + 24 * MB);
    u16* ctx   = (u16*)(ws + 24 * MB);
    u16* QKVb  = (u16*)(ws + 40 * MB);
    float* x1  = (float*)(ws + 40 * MB);
    u16* h2    = (u16*)(ws + 72 * MB);
    u16* ff    = (u16*)(ws + 88 * MB);

    dim3 tb(32, 8);
    transpose4_f2b<<<dim3(32, 32, 4), tb, 0, stream>>>(Wq, Wk, Wv, Wo, WtQKV, WtO);
    transpose_f2b<<<dim3(DFF / 32, DM / 32), tb, 0, stream>>>(W1, Wt1, DM, DFF);
    transpose_f2b<<<dim3(DM / 32, DFF / 32), tb, 0, stream>>>(W2, Wt2, DFF, DM);

    ln_kernel<<<MROWS, 256, 0, stream>>>(x, gamma1, beta1, h);

    gemm_bt<0><<<dim3(MROWS / BM, 3 * DM / BN), 256, 0, stream>>>(
        h, WtQKV, bq, bk, bv, QKVb, nullptr, nullptr, nullptr, MROWS, 3 * DM, DM);

    attn_mfma<<<BB * NH * 32, 256, 0, stream>>>(QKVb, ctx);

    gemm_bt<1><<<dim3(MROWS / BM, DM / BN), 256, 0, stream>>>(
        ctx, WtO, bo, nullptr, nullptr, x1, x, nullptr, nullptr, MROWS, DM, DM);

    ln_kernel<<<MROWS, 256, 0, stream>>>(x1, gamma2, beta2, h2);

    gemm_bt<2><<<dim3(MROWS / BM, DFF / BN), 256, 0, stream>>>(
        h2, Wt1, b1, nullptr, nullptr, ff, nullptr, nullptr, nullptr, MROWS, DFF, DM);

    gemm_bt<3><<<dim3(MROWS / BM, DM / BN), 256, 0, stream>>>(
        ff, Wt2, b2, nullptr, nullptr, out, x1, x, gate, MROWS, DM, DFF);
}

// Round 5
// 552.254 us; speedup vs baseline: 1.0144x; 1.0092x over previous
//
#include <hip/hip_runtime.h>
#include <hip/hip_bf16.h>
#include <cmath>

typedef unsigned short u16;
typedef __attribute__((ext_vector_type(8))) short short8;
typedef __attribute__((ext_vector_type(4))) float f32x4;

#define DM 1024
#define NH 16
#define DH 64
#define DFF 4096
#define BB 4
#define TT 2048
#define MROWS (BB*TT)

__device__ __forceinline__ float bu2f(u16 u) {
    union { float f; unsigned v; } c; c.v = ((unsigned)u) << 16; return c.f;
}
__device__ __forceinline__ u16 f2bu(float f) {
    __hip_bfloat16 h = __float2bfloat16(f);
    union { __hip_bfloat16 h; u16 u; } c; c.h = h; return c.u;
}
__device__ __forceinline__ void async_copy16(const u16* g, u16* l) {
    __builtin_amdgcn_global_load_lds((const __attribute__((address_space(1))) void*)g,
                                     (__attribute__((address_space(3))) void*)l, 16, 0, 0);
}

// ---------------- LayerNorm: fp32 in -> bf16 out ----------------
__global__ void ln_kernel(const float* __restrict__ x, const float* __restrict__ gamma,
                          const float* __restrict__ beta, u16* __restrict__ out)
{
    int row = blockIdx.x;
    int tid = threadIdx.x;
    float4 v4 = ((const float4*)(x + (size_t)row * DM))[tid];
    float v[4] = { v4.x, v4.y, v4.z, v4.w };
    float s = v[0] + v[1] + v[2] + v[3];
    float ss = v[0]*v[0] + v[1]*v[1] + v[2]*v[2] + v[3]*v[3];
    #pragma unroll
    for (int o = 32; o > 0; o >>= 1) { s += __shfl_down(s, o); ss += __shfl_down(ss, o); }
    __shared__ float red[8];
    int w = tid >> 6;
    if ((tid & 63) == 0) { red[w] = s; red[4 + w] = ss; }
    __syncthreads();
    s  = red[0] + red[1] + red[2] + red[3];
    ss = red[4] + red[5] + red[6] + red[7];
    float mu  = s * (1.0f / DM);
    float var = ss * (1.0f / DM) - mu * mu;
    float rstd = rsqrtf(var + 1e-5f);
    float4 g4 = ((const float4*)gamma)[tid];
    float4 b4 = ((const float4*)beta)[tid];
    float g[4] = { g4.x, g4.y, g4.z, g4.w };
    float b[4] = { b4.x, b4.y, b4.z, b4.w };
    ushort4 o4;
    u16* op = (u16*)&o4;
    #pragma unroll
    for (int i = 0; i < 4; i++) op[i] = f2bu((v[i] - mu) * rstd * g[i] + b[i]);
    ((ushort4*)(out + (size_t)row * DM))[tid] = o4;
}

// ---------------- Transposes + fp32->bf16 ----------------
__global__ void transpose4_f2b(const float* __restrict__ w0, const float* __restrict__ w1,
                               const float* __restrict__ w2, const float* __restrict__ w3,
                               u16* __restrict__ outQKV, u16* __restrict__ outO)
{
    __shared__ u16 tile[32][33];
    const float* in = (blockIdx.z == 0) ? w0 : (blockIdx.z == 1) ? w1
                     : (blockIdx.z == 2) ? w2 : w3;
    u16* out = (blockIdx.z < 3) ? (outQKV + (size_t)blockIdx.z * DM * DM) : outO;
    int bx = blockIdx.x * 32;
    int by = blockIdx.y * 32;
    int tx = threadIdx.x, ty = threadIdx.y;  // 32 x 8
    #pragma unroll
    for (int i = 0; i < 32; i += 8)
        tile[ty + i][tx] = f2bu(in[(size_t)(by + ty + i) * DM + bx + tx]);
    __syncthreads();
    #pragma unroll
    for (int i = 0; i < 32; i += 8)
        out[(size_t)(bx + ty + i) * DM + by + tx] = tile[tx][ty + i];
}

__global__ void transpose_f2b(const float* __restrict__ in, u16* __restrict__ out,
                              int R, int C)
{
    __shared__ u16 tile[32][33];
    int bx = blockIdx.x * 32;
    int by = blockIdx.y * 32;
    int tx = threadIdx.x, ty = threadIdx.y;  // 32 x 8
    #pragma unroll
    for (int i = 0; i < 32; i += 8)
        tile[ty + i][tx] = f2bu(in[(size_t)(by + ty + i) * C + bx + tx]);
    __syncthreads();
    #pragma unroll
    for (int i = 0; i < 32; i += 8)
        out[(size_t)(bx + ty + i) * R + by + tx] = tile[tx][ty + i];
}

// ---------------- GEMM 128x128 (verified m97-style), used for N=1024 outputs ----------
#define BM 128
#define BN 128
#define BK 64

template<int EPI>
__global__ void gemm_bt(
    const u16* __restrict__ A, const u16* __restrict__ Bt,
    const float* __restrict__ bias, const float* __restrict__ bias2,
    const float* __restrict__ bias3, void* __restrict__ Cv,
    const float* __restrict__ res, const float* __restrict__ x0,
    const float* __restrict__ gate, int M, int N, int K)
{
    __shared__ __align__(16) u16 As[BM * BK];
    __shared__ __align__(16) u16 Bs[BN * BK];
    int tid = threadIdx.x;
    int lane = tid & 63, wave = tid >> 6;
    int wm = (wave & 1) * 64, wn = (wave >> 1) * 64;
    int lm = lane & 15, quad = lane >> 4;
    size_t row0 = (size_t)blockIdx.x * BM;
    size_t col0 = (size_t)blockIdx.y * BN;

    int sr = tid >> 3;                              // 0..31
    int scol = (((tid & 7) ^ (sr & 7)) * 8);        // swizzled source col
    const u16* Ag = A  + (row0 + sr) * (size_t)K + scol;
    const u16* Bg = Bt + (col0 + sr) * (size_t)K + scol;
    u16* Asl = As + tid * 8;
    u16* Bsl = Bs + tid * 8;

    int fc0 = ((0 * 4 + quad) ^ (lm & 7)) * 8;
    int fc1 = ((1 * 4 + quad) ^ (lm & 7)) * 8;

    f32x4 acc[4][4];
    #pragma unroll
    for (int i = 0; i < 4; i++)
        #pragma unroll
        for (int j = 0; j < 4; j++)
            acc[i][j] = (f32x4){0.f, 0.f, 0.f, 0.f};

    for (int k0 = 0; k0 < K; k0 += BK) {
        __syncthreads();
        async_copy16(Ag + k0,                  Asl);
        async_copy16(Ag + (size_t)32 * K + k0, Asl + 32 * BK);
        async_copy16(Ag + (size_t)64 * K + k0, Asl + 64 * BK);
        async_copy16(Ag + (size_t)96 * K + k0, Asl + 96 * BK);
        async_copy16(Bg + k0,                  Bsl);
        async_copy16(Bg + (size_t)32 * K + k0, Bsl + 32 * BK);
        async_copy16(Bg + (size_t)64 * K + k0, Bsl + 64 * BK);
        async_copy16(Bg + (size_t)96 * K + k0, Bsl + 96 * BK);
        __syncthreads();
        #pragma unroll
        for (int ks = 0; ks < 2; ks++) {
            int fc = ks ? fc1 : fc0;
            short8 af[4], bfr[4];
            #pragma unroll
            for (int t = 0; t < 4; t++) {
                af[t]  = *(const short8*)&As[(wm + t * 16 + lm) * BK + fc];
                bfr[t] = *(const short8*)&Bs[(wn + t * 16 + lm) * BK + fc];
            }
            #pragma unroll
            for (int mt = 0; mt < 4; mt++)
                #pragma unroll
                for (int nt = 0; nt < 4; nt++)
                    acc[mt][nt] = __builtin_amdgcn_mfma_f32_16x16x32_bf16(
                        af[mt], bfr[nt], acc[mt][nt], 0, 0, 0);
        }
    }

    u16*   C16 = (u16*)Cv;
    float* Cf  = (float*)Cv;

    const float* bb = bias;
    size_t csub = 0;
    if (EPI == 0 && bias2 != nullptr) {
        size_t cbase = col0 + wn;
        if (cbase >= 2048)      { bb = bias3; csub = 2048; }
        else if (cbase >= 1024) { bb = bias2; csub = 1024; }
    }

    #pragma unroll
    for (int mt = 0; mt < 4; mt++) {
        #pragma unroll
        for (int nt = 0; nt < 4; nt++) {
            #pragma unroll
            for (int r = 0; r < 4; r++) {
                size_t row = row0 + wm + mt * 16 + quad * 4 + r;
                size_t col = col0 + wn + nt * 16 + lm;
                size_t idx = row * (size_t)N + col;
                float v = acc[mt][nt][r] + bb[col - csub];
                if (EPI == 0) {
                    C16[idx] = f2bu(v);
                } else if (EPI == 1) {
                    Cf[idx] = v + res[idx];
                } else if (EPI == 2) {
                    v = 0.5f * v * (1.0f + erff(v * 0.70710678118f));
                    C16[idx] = f2bu(v);
                } else {
                    float xv  = x0[idx];
                    float x1v = res[idx];
                    float g   = gate[row >> 11];
                    Cf[idx] = xv + g * (x1v + v - xv);
                }
            }
        }
    }
}

// ---------------- GEMM 256x256, 8-wave, 4-phase/K-tile counted-vmcnt pipeline ----------
// T2 (granule-XOR swizzle, same involution as the proven 128^2 kernel) + T3/T4
// (per-phase barrier schedule, vmcnt(4) never drained mid-loop) + T5 (setprio).
// Staging order per K-tile t (into buf t+1&1): ph0:A-h0, ph1:B-h0, ph2:B-h1, ph3:A-h1.
// vmcnt ledger (2 loads/half): tile-boundary outstanding = 8 (the next tile's 4 halves).
//   ph0 vmcnt(4) -> lands B-h1(cur)   [needed by ph1's ds_read]
//   ph1 vmcnt(4) -> lands A-h1(cur)   [needed by ph2's ds_read]
//   ph3 vmcnt(4) -> lands A-h0,B-h0(next) [needed by next tile's ph0]
// Last tile stages nothing: ph0 vmcnt(2), ph1 vmcnt(0).
// Raw s_barrier (NOT __syncthreads: that drains vmcnt(0) = the m97 stall);
// sched_barrier(0) after each barrier pins phase boundaries (rule #18-style).
#define BM2 256
#define BN2 256
#define BK2 64

template<int EPI>
__global__ __launch_bounds__(512, 2) void gemm_bt256(
    const u16* __restrict__ A, const u16* __restrict__ Bt,
    const float* __restrict__ bias, const float* __restrict__ bias2,
    const float* __restrict__ bias3, void* __restrict__ Cv,
    int M, int N, int K)
{
    __shared__ __align__(16) u16 LA[2][2][128][64];   // [buf][half][row][col] 64KB
    __shared__ __align__(16) u16 LB[2][2][128][64];   // 64KB

    int tid = threadIdx.x;
    int lane = tid & 63, wave = tid >> 6;
    int wm = wave >> 2, wn = wave & 3;               // 2 x 4 wave grid
    int lm = lane & 15, quad = lane >> 4;

    size_t row0 = (size_t)blockIdx.x * BM2;
    size_t col0 = (size_t)blockIdx.y * BN2;

    // staging map: wave w covers rows w*8..w*8+7 of a 64-row issue; lane&7 = granule.
    int srow = wave * 8 + (lane >> 3);               // 0..63
    int scol = ((lane & 7) ^ ((lane >> 3) & 7)) * 8; // pre-swizzled source granule
    const u16* Ag = A  + (row0 + srow) * (size_t)K + scol;
    const u16* Bg = Bt + (col0 + srow) * (size_t)K + scol;

    int fc0 = (quad ^ (lm & 7)) * 8;                 // frag-read swizzled granules
    int fc1 = ((4 + quad) ^ (lm & 7)) * 8;

    f32x4 acc[8][4];
    #pragma unroll
    for (int i = 0; i < 8; i++)
        #pragma unroll
        for (int j = 0; j < 4; j++)
            acc[i][j] = (f32x4){0.f, 0.f, 0.f, 0.f};

    const int NT = K / BK2;

    // ---- prologue: stage tile0 (A0,B0,B1,A1), land A0+B0 ----
    async_copy16(Ag,                   &LA[0][0][0][0]  + tid * 8);
    async_copy16(Ag + (size_t)64 * K,  &LA[0][0][64][0] + tid * 8);
    async_copy16(Bg,                   &LB[0][0][0][0]  + tid * 8);
    async_copy16(Bg + (size_t)64 * K,  &LB[0][0][64][0] + tid * 8);
    async_copy16(Bg + (size_t)128 * K, &LB[0][1][0][0]  + tid * 8);
    async_copy16(Bg + (size_t)192 * K, &LB[0][1][64][0] + tid * 8);
    async_copy16(Ag + (size_t)128 * K, &LA[0][1][0][0]  + tid * 8);
    async_copy16(Ag + (size_t)192 * K, &LA[0][1][64][0] + tid * 8);
    asm volatile("s_waitcnt vmcnt(4)" ::: "memory");
    __builtin_amdgcn_s_barrier();
    __builtin_amdgcn_sched_barrier(0);

    for (int t = 0; t < NT; ++t) {
        int cur = t & 1, nb = cur ^ 1;
        bool hn = (t + 1 < NT);
        size_t koff = (size_t)(t + 1) * BK2;

        short8 af[4][2], bf[2][2], bg[2][2];

        // ===== phase 0: read A-h0 + B-h0; stage A-h0(next); MFMA Q(0,0) =====
        #pragma unroll
        for (int mf = 0; mf < 4; mf++) {
            af[mf][0] = *(const short8*)&LA[cur][0][wm * 64 + mf * 16 + lm][fc0];
            af[mf][1] = *(const short8*)&LA[cur][0][wm * 64 + mf * 16 + lm][fc1];
        }
        #pragma unroll
        for (int nf = 0; nf < 2; nf++) {
            bf[nf][0] = *(const short8*)&LB[cur][0][wn * 32 + nf * 16 + lm][fc0];
            bf[nf][1] = *(const short8*)&LB[cur][0][wn * 32 + nf * 16 + lm][fc1];
        }
        if (hn) {
            async_copy16(Ag + koff,                   &LA[nb][0][0][0]  + tid * 8);
            async_copy16(Ag + (size_t)64 * K + koff,  &LA[nb][0][64][0] + tid * 8);
            asm volatile("s_waitcnt vmcnt(4)" ::: "memory");
        } else {
            asm volatile("s_waitcnt vmcnt(2)" ::: "memory");
        }
        __builtin_amdgcn_s_barrier();
        __builtin_amdgcn_sched_barrier(0);
        __builtin_amdgcn_s_setprio(1);
        #pragma unroll
        for (int mf = 0; mf < 4; mf++)
            #pragma unroll
            for (int nf = 0; nf < 2; nf++) {
                acc[mf][nf] = __builtin_amdgcn_mfma_f32_16x16x32_bf16(af[mf][0], bf[nf][0], acc[mf][nf], 0, 0, 0);
                acc[mf][nf] = __builtin_amdgcn_mfma_f32_16x16x32_bf16(af[mf][1], bf[nf][1], acc[mf][nf], 0, 0, 0);
            }
        __builtin_amdgcn_s_setprio(0);
        __builtin_amdgcn_s_barrier();
        __builtin_amdgcn_sched_barrier(0);

        // ===== phase 1: read B-h1; stage B-h0(next); MFMA Q(0,1) =====
        #pragma unroll
        for (int nf = 0; nf < 2; nf++) {
            bg[nf][0] = *(const short8*)&LB[cur][1][wn * 32 + nf * 16 + lm][fc0];
            bg[nf][1] = *(const short8*)&LB[cur][1][wn * 32 + nf * 16 + lm][fc1];
        }
        if (hn) {
            async_copy16(Bg + koff,                   &LB[nb][0][0][0]  + tid * 8);
            async_copy16(Bg + (size_t)64 * K + koff,  &LB[nb][0][64][0] + tid * 8);
            asm volatile("s_waitcnt vmcnt(4)" ::: "memory");
        } else {
            asm volatile("s_waitcnt vmcnt(0)" ::: "memory");
        }
        __builtin_amdgcn_s_barrier();
        __builtin_amdgcn_sched_barrier(0);
        __builtin_amdgcn_s_setprio(1);
        #pragma unroll
        for (int mf = 0; mf < 4; mf++)
            #pragma unroll
            for (int nf = 0; nf < 2; nf++) {
                acc[mf][2 + nf] = __builtin_amdgcn_mfma_f32_16x16x32_bf16(af[mf][0], bg[nf][0], acc[mf][2 + nf], 0, 0, 0);
                acc[mf][2 + nf] = __builtin_amdgcn_mfma_f32_16x16x32_bf16(af[mf][1], bg[nf][1], acc[mf][2 + nf], 0, 0, 0);
            }
        __builtin_amdgcn_s_setprio(0);
        __builtin_amdgcn_s_barrier();
        __builtin_amdgcn_sched_barrier(0);

        // ===== phase 2: read A-h1 (overwrite af); stage B-h1(next); MFMA Q(1,1) =====
        #pragma unroll
        for (int mf = 0; mf < 4; mf++) {
            af[mf][0] = *(const short8*)&LA[cur][1][wm * 64 + mf * 16 + lm][fc0];
            af[mf][1] = *(const short8*)&LA[cur][1][wm * 64 + mf * 16 + lm][fc1];
        }
        if (hn) {
            async_copy16(Bg + (size_t)128 * K + koff, &LB[nb][1][0][0]  + tid * 8);
            async_copy16(Bg + (size_t)192 * K + koff, &LB[nb][1][64][0] + tid * 8);
        }
        __builtin_amdgcn_s_barrier();
        __builtin_amdgcn_sched_barrier(0);
        __builtin_amdgcn_s_setprio(1);
        #pragma unroll
        for (int mf = 0; mf < 4; mf++)
            #pragma unroll
            for (int nf = 0; nf < 2; nf++) {
                acc[4 + mf][2 + nf] = __builtin_amdgcn_mfma_f32_16x16x32_bf16(af[mf][0], bg[nf][0], acc[4 + mf][2 + nf], 0, 0, 0);
                acc[4 + mf][2 + nf] = __builtin_amdgcn_mfma_f32_16x16x32_bf16(af[mf][1], bg[nf][1], acc[4 + mf][2 + nf], 0, 0, 0);
            }
        __builtin_amdgcn_s_setprio(0);
        __builtin_amdgcn_s_barrier();
        __builtin_amdgcn_sched_barrier(0);

        // ===== phase 3: re-read B-h0; stage A-h1(next); MFMA Q(1,0) =====
        #pragma unroll
        for (int nf = 0; nf < 2; nf++) {
            bf[nf][0] = *(const short8*)&LB[cur][0][wn * 32 + nf * 16 + lm][fc0];
            bf[nf][1] = *(const short8*)&LB[cur][0][wn * 32 + nf * 16 + lm][fc1];
        }
        if (hn) {
            async_copy16(Ag + (size_t)128 * K + koff, &LA[nb][1][0][0]  + tid * 8);
            async_copy16(Ag + (size_t)192 * K + koff, &LA[nb][1][64][0] + tid * 8);
            asm volatile("s_waitcnt vmcnt(4)" ::: "memory");
        }
        __builtin_amdgcn_s_barrier();
        __builtin_amdgcn_sched_barrier(0);
        __builtin_amdgcn_s_setprio(1);
        #pragma unroll
        for (int mf = 0; mf < 4; mf++)
            #pragma unroll
            for (int nf = 0; nf < 2; nf++) {
                acc[4 + mf][nf] = __builtin_amdgcn_mfma_f32_16x16x32_bf16(af[mf][0], bf[nf][0], acc[4 + mf][nf], 0, 0, 0);
                acc[4 + mf][nf] = __builtin_amdgcn_mfma_f32_16x16x32_bf16(af[mf][1], bf[nf][1], acc[4 + mf][nf], 0, 0, 0);
            }
        __builtin_amdgcn_s_setprio(0);
        __builtin_amdgcn_s_barrier();
        __builtin_amdgcn_sched_barrier(0);
    }

    // ---- epilogue ----
    u16* C16 = (u16*)Cv;
    const float* bb = bias;
    size_t csub = 0;
    if (EPI == 0 && bias2 != nullptr) {
        if (col0 >= 2048)      { bb = bias3; csub = 2048; }
        else if (col0 >= 1024) { bb = bias2; csub = 1024; }
    }
    #pragma unroll
    for (int mq = 0; mq < 8; mq++) {
        #pragma unroll
        for (int nq = 0; nq < 4; nq++) {
            #pragma unroll
            for (int r = 0; r < 4; r++) {
                size_t row = row0 + (size_t)(mq >> 2) * 128 + wm * 64 + (mq & 3) * 16 + quad * 4 + r;
                size_t col = col0 + (size_t)(nq >> 1) * 128 + wn * 32 + (nq & 1) * 16 + lm;
                float v = acc[mq][nq][r] + bb[col - csub];
                if (EPI == 2)
                    v = 0.5f * v * (1.0f + erff(v * 0.70710678118f));
                C16[row * (size_t)N + col] = f2bu(v);
            }
        }
    }
}

// ---------------- MFMA flash attention (round-0 verified version, 118us) ----------------
#define AVS 72

__global__ __launch_bounds__(256, 4) void attn_mfma(
    const u16* __restrict__ QKV, u16* __restrict__ ctx)
{
    __shared__ __align__(16) u16 Kl[64][AVS];      // [key][dim]
    __shared__ __align__(16) u16 Vt[64][AVS];      // [dim][key]
    __shared__ __align__(16) u16 Pl[4][16][AVS];   // per-wave P[q][k]

    const int LD = 3 * DM;
    int tid = threadIdx.x, lane = tid & 63, w = tid >> 6;
    int lm = lane & 15, quad = lane >> 4;

    int bi = blockIdx.x;
    int pair = bi & 15, h = (bi >> 4) & 15, b = bi >> 8;
    int t1 = 31 - pair, t2 = pair;

    const size_t hoff = (size_t)h * DH;
    const u16* Qp = QKV + (size_t)b * TT * LD + hoff;
    const u16* Kp = Qp + DM;
    const u16* Vp = Qp + 2 * DM;

    short8 aqA[2], aqB[2];
    #pragma unroll
    for (int dc = 0; dc < 2; dc++) {
        aqA[dc] = *(const short8*)(Qp + (size_t)(t1 * 64 + w * 16 + lm) * LD + dc * 32 + quad * 8);
        aqB[dc] = *(const short8*)(Qp + (size_t)(t2 * 64 + w * 16 + lm) * LD + dc * 32 + quad * 8);
    }

    int kkey = tid & 63, kdim = (tid >> 6) * 16;       // K: 1 key x 16 dims
    int vkey = (tid & 31) * 2, vdim = (tid >> 5) * 8;  // V: 2 keys x 8 dims

    const u16* kb0 = Kp + (size_t)kkey * LD + kdim;
    const u16* vb0 = Vp + (size_t)vkey * LD + vdim;
    const u16* vb1 = Vp + (size_t)(vkey + 1) * LD + vdim;

    const float sc = 0.18033688011f;   // log2(e)/8
    const float FM = 24.0f;            // fixed max (exp2 domain)
    const short s1 = (short)0x3F80;    // bf16 1.0
    const short8 ones = (short8){s1, s1, s1, s1, s1, s1, s1, s1};

    uint4 kr0 = *(const uint4*)(kb0);
    uint4 kr1 = *(const uint4*)(kb0 + 8);
    uint4 vr0 = *(const uint4*)(vb0);
    uint4 vr1 = *(const uint4*)(vb1);

    #pragma unroll
    for (int ti = 0; ti < 2; ti++) {
        int tcur = (ti == 0) ? t1 : t2;
        int nch = tcur + 1;
        int q0 = tcur * 64;
        int qw = q0 + w * 16;
        short8 a0 = (ti == 0) ? aqA[0] : aqB[0];
        short8 a1 = (ti == 0) ? aqA[1] : aqB[1];
        int qv = qw + lm;

        f32x4 o[4], o5;
        #pragma unroll
        for (int ds = 0; ds < 4; ds++) o[ds] = (f32x4){0.f, 0.f, 0.f, 0.f};
        o5 = (f32x4){0.f, 0.f, 0.f, 0.f};

        for (int c = 0; c < nch; c++) {
            int kb = c * 64;
            __syncthreads();
            *(uint4*)&Kl[kkey][kdim]     = kr0;
            *(uint4*)&Kl[kkey][kdim + 8] = kr1;
            {
                const u16* p0 = (const u16*)&vr0;
                const u16* p1 = (const u16*)&vr1;
                #pragma unroll
                for (int j = 0; j < 8; j++) {
                    ushort2 pk = { p0[j], p1[j] };
                    *(ushort2*)&Vt[vdim + j][vkey] = pk;
                }
            }
            __syncthreads();

            {
                size_t offn = (c + 1 < nch) ? (size_t)(c + 1) * 64 * LD : 0;
                kr0 = *(const uint4*)(kb0 + offn);
                kr1 = *(const uint4*)(kb0 + offn + 8);
                vr0 = *(const uint4*)(vb0 + offn);
                vr1 = *(const uint4*)(vb1 + offn);
            }

            // S^T = K Q^T
            f32x4 s[4];
            #pragma unroll
            for (int ks = 0; ks < 4; ks++) s[ks] = (f32x4){0.f, 0.f, 0.f, 0.f};
            #pragma unroll
            for (int ks = 0; ks < 4; ks++) {
                short8 k0 = *(const short8*)&Kl[ks * 16 + lm][quad * 8];
                short8 k1 = *(const short8*)&Kl[ks * 16 + lm][32 + quad * 8];
                s[ks] = __builtin_amdgcn_mfma_f32_16x16x32_bf16(k0, a0, s[ks], 0, 0, 0);
                s[ks] = __builtin_amdgcn_mfma_f32_16x16x32_bf16(k1, a1, s[ks], 0, 0, 0);
            }

            // P = exp2(s*sc - FM); causal mask -> 0; packed b64 write
            bool mz = (kb + 63 > qw);
            #pragma unroll
            for (int ks = 0; ks < 4; ks++) {
                int kbase = kb + ks * 16 + quad * 4;
                ushort4 pk;
                u16* pp = (u16*)&pk;
                #pragma unroll
                for (int r = 0; r < 4; r++) {
                    float v = s[ks][r] * sc - FM;
                    if (mz && (kbase + r > qv)) v = -INFINITY;
                    pp[r] = f2bu(exp2f(v));
                }
                *(ushort4*)&Pl[w][lm][ks * 16 + quad * 4] = pk;
            }

            // ctx += P V ; l += P * ones
            #pragma unroll
            for (int kc = 0; kc < 2; kc++) {
                short8 ap = *(const short8*)&Pl[w][lm][kc * 32 + quad * 8];
                #pragma unroll
                for (int ds = 0; ds < 4; ds++) {
                    short8 bv = *(const short8*)&Vt[ds * 16 + lm][kc * 32 + quad * 8];
                    o[ds] = __builtin_amdgcn_mfma_f32_16x16x32_bf16(ap, bv, o[ds], 0, 0, 0);
                }
                o5 = __builtin_amdgcn_mfma_f32_16x16x32_bf16(ap, ones, o5, 0, 0, 0);
            }
        }

        float inv[4];
        #pragma unroll
        for (int r = 0; r < 4; r++) inv[r] = 1.0f / o5[r];
        #pragma unroll
        for (int ds = 0; ds < 4; ds++)
            #pragma unroll
            for (int r = 0; r < 4; r++) {
                size_t row = (size_t)(b * TT + qw + quad * 4 + r);
                ctx[row * DM + hoff + ds * 16 + lm] = f2bu(o[ds][r] * inv[r]);
            }
    }
}

extern "C" void kernel_launch(void* const* d_in, const int* in_sizes, int n_in,
                              void* d_out, int out_size, void* d_ws, size_t ws_size,
                              hipStream_t stream)
{
    const float* x    = (const float*)d_in[0];
    const float* gate = (const float*)d_in[1];
    const float* Wq   = (const float*)d_in[2];
    const float* bq   = (const float*)d_in[3];
    const float* Wk   = (const float*)d_in[4];
    const float* bk   = (const float*)d_in[5];
    const float* Wv   = (const float*)d_in[6];
    const float* bv   = (const float*)d_in[7];
    const float* Wo   = (const float*)d_in[8];
    const float* bo   = (const float*)d_in[9];
    const float* W1   = (const float*)d_in[10];
    const float* b1   = (const float*)d_in[11];
    const float* W2   = (const float*)d_in[12];
    const float* b2   = (const float*)d_in[13];
    const float* gamma1 = (const float*)d_in[14];
    const float* beta1  = (const float*)d_in[15];
    const float* gamma2 = (const float*)d_in[16];
    const float* beta2  = (const float*)d_in[17];
    float* out = (float*)d_out;

    char* ws = (char*)d_ws;
    const size_t MB = 1024 * 1024;
    u16* WtQKV = (u16*)(ws + 0 * MB);
    u16* WtO   = (u16*)(ws + 6 * MB);
    u16* Wt1   = (u16*)(ws + 8 * MB);
    u16* Wt2   = (u16*)(ws + 16 * MB);
    u16* h     = (u16*)(ws + 24 * MB);
    u16* ctx   = (u16*)(ws + 24 * MB);
    u16* QKVb  = (u16*)(ws + 40 * MB);
    float* x1  = (float*)(ws + 40 * MB);
    u16* h2    = (u16*)(ws + 72 * MB);
    u16* ff    = (u16*)(ws + 88 * MB);

    dim3 tb(32, 8);
    transpose4_f2b<<<dim3(32, 32, 4), tb, 0, stream>>>(Wq, Wk, Wv, Wo, WtQKV, WtO);
    transpose_f2b<<<dim3(DFF / 32, DM / 32), tb, 0, stream>>>(W1, Wt1, DM, DFF);
    transpose_f2b<<<dim3(DM / 32, DFF / 32), tb, 0, stream>>>(W2, Wt2, DFF, DM);

    ln_kernel<<<MROWS, 256, 0, stream>>>(x, gamma1, beta1, h);

    gemm_bt256<0><<<dim3(MROWS / BM2, 3 * DM / BN2), 512, 0, stream>>>(
        h, WtQKV, bq, bk, bv, QKVb, MROWS, 3 * DM, DM);

    attn_mfma<<<BB * NH * 16, 256, 0, stream>>>(QKVb, ctx);

    gemm_bt<1><<<dim3(MROWS / BM, DM / BN), 256, 0, stream>>>(
        ctx, WtO, bo, nullptr, nullptr, x1, x, nullptr, nullptr, MROWS, DM, DM);

    ln_kernel<<<MROWS, 256, 0, stream>>>(x1, gamma2, beta2, h2);

    gemm_bt256<2><<<dim3(MROWS / BM2, DFF / BN2), 512, 0, stream>>>(
        h2, Wt1, b1, nullptr, nullptr, ff, MROWS, DFF, DM);

    gemm_bt<3><<<dim3(MROWS / BM, DM / BN), 256, 0, stream>>>(
        ff, Wt2, b2, nullptr, nullptr, out, x1, x, gate, MROWS, DM, DFF);
}